// Round 14
// baseline (118.772 us; speedup 1.0000x reference)
//
#include <hip/hip_runtime.h>
#include <cmath>

#define NB 128     // batch
#define CC 1024    // classes
#define CAP 64     // max nnz per row of R (expected ~11, P(>63) negligible)

// ---------------------------------------------------------------------------
// K1: CSR-compact R rows (blocks 0..1023) + zero the accumulator region
// (blocks 1024..1039: accI[1024]|accC[1024]|accB|ticket|pad = 4096 words).
// ---------------------------------------------------------------------------
__global__ __launch_bounds__(256) void csr_zero(
        const float* __restrict__ R, int* __restrict__ cnt,
        int* __restrict__ cols, float* __restrict__ vals,
        float* __restrict__ acc) {
    const int b = blockIdx.x, tx = threadIdx.x;
    if (b < CC) {
        __shared__ int s_cnt;
        if (tx == 0) s_cnt = 0;
        __syncthreads();
        const float4 v4 = ((const float4*)(R + (size_t)b * CC))[tx];
        const int j0 = tx * 4;
        #pragma unroll
        for (int u = 0; u < 4; ++u) {
            const float v = (u == 0) ? v4.x : (u == 1) ? v4.y : (u == 2) ? v4.z : v4.w;
            if (v != 0.0f) {
                const int pos = atomicAdd(&s_cnt, 1);
                if (pos < CAP) { cols[b * CAP + pos] = j0 + u; vals[b * CAP + pos] = v; }
            }
        }
        __syncthreads();
        if (tx == 0) cnt[b] = min(s_cnt, CAP);
    } else {
        acc[(b - CC) * 256 + tx] = 0.0f;          // 16*256 = 4096 words
    }
}

// ---------------------------------------------------------------------------
// K2: thread t -> (n = t>>10, i = t&1023); block = one batch row n, 256
// consecutive classes -> coalesced y/mcm_out, gathers within one 4KB L1 h-row.
//   p_j = sigmoid(h[n,j]) on the fly (bit-identical formula; VALU is idle).
//   m = max v*p_j ; mp = max over y[n,j]==1 (== dense masked MCM, products>=0).
//   h* = y ? mp : m; dice I/card via per-class device atomics (order noise
//   ~1e-6); BCE block-reduced, one atomic per block.
//   Ticket epilogue: last of 512 blocks computes dice mean + loss in-kernel.
//   No spin-wait anywhere: non-last blocks exit; no deadlock possible.
// ---------------------------------------------------------------------------
__global__ __launch_bounds__(256) void mcm_loss(
        const float* __restrict__ h, const int* __restrict__ y,
        const int* __restrict__ cnt, const int* __restrict__ cols,
        const float* __restrict__ vals,
        float* __restrict__ mcm_out, float* __restrict__ out0,
        float* __restrict__ accI, float* __restrict__ accC,
        float* __restrict__ accB, int* __restrict__ ticket) {
    const int t = blockIdx.x * 256 + threadIdx.x;
    const int tx = threadIdx.x;
    const int n = t >> 10;
    const int i = t & (CC - 1);
    const float* __restrict__ hrow = h + n * CC;
    const int*   __restrict__ yrow = y + n * CC;

    const int rc = cnt[i];
    float m = 0.0f, mp = 0.0f;
    for (int k = 0; k < rc; ++k) {
        const int   j  = cols[i * CAP + k];
        const float v  = vals[i * CAP + k];
        const float pj = 1.0f / (1.0f + expf(-hrow[j]));
        const float vp = v * pj;
        m = fmaxf(m, vp);
        if (yrow[j]) mp = fmaxf(mp, vp);
    }
    mcm_out[t] = m;                               // coalesced

    const int   yv = yrow[i];                     // == y[t], coalesced
    const float hv = yv ? mp : m;                 // h_star
    if (yv) atomicAdd(accI + i, hv);
    atomicAdd(accC + i, hv + (float)yv);

    float lg = yv ? logf(hv) : log1pf(-hv);       // hv in (0,1): R diagonal
    lg = fmaxf(lg, -100.0f);
    #pragma unroll
    for (int off = 32; off > 0; off >>= 1) lg += __shfl_down(lg, off);
    __shared__ float sb[4];
    __shared__ int s_last;
    const int wid = tx >> 6, lane = tx & 63;
    if (lane == 0) sb[wid] = lg;

    __threadfence();                              // order my atomics
    __syncthreads();                              // all lanes' atomics drained

    if (tx == 0) {
        atomicAdd(accB, sb[0] + sb[1] + sb[2] + sb[3]);
        __threadfence();
        s_last = (atomicAdd(ticket, 1) == (int)gridDim.x - 1);
    }
    __syncthreads();

    // ---- last block: dice mean over classes + final loss ----
    if (s_last) {
        __threadfence();                          // acquire
        float ds = 0.0f;
        for (int c = tx; c < CC; c += 256) {
            const float I  = __hip_atomic_load(accI + c, __ATOMIC_RELAXED, __HIP_MEMORY_SCOPE_AGENT);
            const float Cd = __hip_atomic_load(accC + c, __ATOMIC_RELAXED, __HIP_MEMORY_SCOPE_AGENT);
            ds += (I > 0.0f) ? (1.0f - 2.0f * I / fmaxf(Cd, 1e-7f)) : 0.0f;
        }
        #pragma unroll
        for (int off = 32; off > 0; off >>= 1) ds += __shfl_down(ds, off);
        __shared__ float sd[4];
        if (lane == 0) sd[wid] = ds;
        __syncthreads();
        if (tx == 0) {
            const float bs = __hip_atomic_load(accB, __ATOMIC_RELAXED, __HIP_MEMORY_SCOPE_AGENT);
            out0[0] = (sd[0] + sd[1] + sd[2] + sd[3]) / (float)CC
                      - bs / (float)(NB * CC);
        }
    }
}

// ---------------------------------------------------------------------------
extern "C" void kernel_launch(void* const* d_in, const int* in_sizes, int n_in,
                              void* d_out, int out_size, void* d_ws, size_t ws_size,
                              hipStream_t stream) {
    const float* h = (const float*)d_in[0];
    const int*   y = (const int*)d_in[1];
    const float* R = (const float*)d_in[2];
    float* out = (float*)d_out;          // out[0]=loss, out[1..]=mcm (N,C)

    // ws: cnt[1024] | cols[CC*CAP] | vals[CC*CAP] | acc[4096]
    int*   cnt    = (int*)d_ws;
    int*   cols   = cnt + CC;
    float* vals   = (float*)(cols + CC * CAP);
    float* acc    = vals + CC * CAP;     // accI|accC|accB|ticket (zeroed by K1)
    float* accI   = acc;
    float* accC   = acc + CC;
    float* accB   = acc + 2 * CC;
    int*   ticket = (int*)(acc + 2 * CC + 1);

    csr_zero<<<CC + 16, 256, 0, stream>>>(R, cnt, cols, vals, acc);
    mcm_loss<<<(NB * CC) / 256, 256, 0, stream>>>(h, y, cnt, cols, vals,
                                                  out + 1, out, accI, accC,
                                                  accB, ticket);
}